// Round 1
// baseline (879.893 us; speedup 1.0000x reference)
//
#include <hip/hip_runtime.h>
#include <hip/hip_bf16.h>

// dims (fixed): T=4, B=1024, WH=WW=8, C=256, NH=8, HD=32
// tokens per timestep G = B*64 = 65536 ; plane = G*256 = 16777216 elements
static constexpr int  T4    = 4;
static constexpr int  G     = 65536;
static constexpr long PLANE = 16777216L;

// ---------------- prep: transposed weights into workspace ----------------
// WqT/WkT: bf16 [c][j] (coalesced column gathers), WpT: f32 [c][j]
__global__ void prep_kernel(const float* __restrict__ Wq, const float* __restrict__ Wk,
                            const float* __restrict__ Wp,
                            __hip_bfloat16* __restrict__ WqT, __hip_bfloat16* __restrict__ WkT,
                            float* __restrict__ WpT)
{
    int c = blockIdx.x;      // 0..255
    int j = threadIdx.x;     // 0..255
    int idx = c * 256 + j;
    WqT[idx] = __float2bfloat16(Wq[j * 256 + c]);
    WkT[idx] = __float2bfloat16(Wk[j * 256 + c]);
    WpT[idx] = Wp[j * 256 + c];
}

// ---------------- k1: xs = lif(x), stored as 256-bit masks per (t,token) ----------------
// Bit-exact LIF: v = v + (x - v)*0.5 (halving is exact), spike = (v-1 >= 0), hard reset.
__global__ __launch_bounds__(256) void lif_x_kernel(const float* __restrict__ x,
                                                    unsigned long long* __restrict__ XS)
{
    int g    = blockIdx.x;       // token (b*64+hw)
    int c    = threadIdx.x;      // channel
    int lane = c & 63;
    int w    = c >> 6;           // 64-channel word
    const float* px = x + (long)g * 256 + c;
    float v = 0.0f;
    #pragma unroll
    for (int t = 0; t < T4; ++t) {
        float xt = px[t * PLANE];
        v = v + (xt - v) * 0.5f;
        bool s = (v - 1.0f) >= 0.0f;
        unsigned long long b = __ballot(s);
        if (s) v = 0.0f;
        if (lane == 0) XS[((long)t * G + g) * 4 + w] = b;
    }
}

// ---------------- k2: sparse q-GEMM + LIF + att-token + attn masks ----------------
// One wave per token-group; lane covers j = {lane, lane+64, lane+128, lane+192}.
// att chunk (32 consecutive channels) sums via ballot+popc halves (exact integers).
// k-path (needs att spike) is a wave-uniform rare branch reading WkT from global.
__global__ __launch_bounds__(256) void qk_att_kernel(
    const unsigned long long* __restrict__ XS,
    unsigned* __restrict__ AM,
    const __hip_bfloat16* __restrict__ WqT,
    const __hip_bfloat16* __restrict__ WkT,
    const float* __restrict__ pos)
{
    int lane = threadIdx.x & 63;
    int wv   = threadIdx.x >> 6;
    int wid  = blockIdx.x * 4 + wv;     // 8192 waves total
    bool lohalf = lane < 32;

    for (int gi = 0; gi < 8; ++gi) {
        int g  = wid * 8 + gi;          // 0..65535
        int hw = g & 63;

        unsigned long long m[4][4];
        #pragma unroll
        for (int t = 0; t < 4; ++t)
            #pragma unroll
            for (int w = 0; w < 4; ++w)
                m[t][w] = XS[((long)t * G + g) * 4 + w];

        float vq0 = 0.f, vq1 = 0.f, vq2 = 0.f, vq3 = 0.f;
        float va0 = 0.f, va1 = 0.f, va2 = 0.f, va3 = 0.f;
        unsigned attb = 0u;             // bit t*4+i = att spike for lane's chunk

        #pragma unroll
        for (int t = 0; t < 4; ++t) {
            float q0 = 0.f, q1 = 0.f, q2 = 0.f, q3 = 0.f;
            #pragma unroll
            for (int w = 0; w < 4; ++w) {
                unsigned long long mm = m[t][w];
                int cbase = w * 64;
                while (mm) {
                    int b = __ffsll(mm) - 1;
                    mm &= (mm - 1);
                    const __hip_bfloat16* p = WqT + (cbase + b) * 256 + lane;
                    q0 += __bfloat162float(p[0]);
                    q1 += __bfloat162float(p[64]);
                    q2 += __bfloat162float(p[128]);
                    q3 += __bfloat162float(p[192]);
                }
            }
            vq0 = vq0 + (q0 - vq0) * 0.5f; bool s0 = (vq0 - 1.0f) >= 0.0f; if (s0) vq0 = 0.0f;
            vq1 = vq1 + (q1 - vq1) * 0.5f; bool s1 = (vq1 - 1.0f) >= 0.0f; if (s1) vq1 = 0.0f;
            vq2 = vq2 + (q2 - vq2) * 0.5f; bool s2 = (vq2 - 1.0f) >= 0.0f; if (s2) vq2 = 0.0f;
            vq3 = vq3 + (q3 - vq3) * 0.5f; bool s3 = (vq3 - 1.0f) >= 0.0f; if (s3) vq3 = 0.0f;

            unsigned long long b0 = __ballot(s0);
            unsigned long long b1 = __ballot(s1);
            unsigned long long b2 = __ballot(s2);
            unsigned long long b3 = __ballot(s3);
            float c0  = (float)__popc(lohalf ? (unsigned)b0 : (unsigned)(b0 >> 32));
            float c1  = (float)__popc(lohalf ? (unsigned)b1 : (unsigned)(b1 >> 32));
            float c2f = (float)__popc(lohalf ? (unsigned)b2 : (unsigned)(b2 >> 32));
            float c3  = (float)__popc(lohalf ? (unsigned)b3 : (unsigned)(b3 >> 32));

            va0 = va0 + (c0  - va0) * 0.5f; bool a0 = (va0 - 1.0f) >= 0.0f; if (a0) va0 = 0.0f;
            va1 = va1 + (c1  - va1) * 0.5f; bool a1 = (va1 - 1.0f) >= 0.0f; if (a1) va1 = 0.0f;
            va2 = va2 + (c2f - va2) * 0.5f; bool a2 = (va2 - 1.0f) >= 0.0f; if (a2) va2 = 0.0f;
            va3 = va3 + (c3  - va3) * 0.5f; bool a3 = (va3 - 1.0f) >= 0.0f; if (a3) va3 = 0.0f;

            attb |= (a0 ? 1u : 0u) << (t * 4 + 0);
            attb |= (a1 ? 1u : 0u) << (t * 4 + 1);
            attb |= (a2 ? 1u : 0u) << (t * 4 + 2);
            attb |= (a3 ? 1u : 0u) << (t * 4 + 3);
        }

        bool anyatt = (__ballot(attb != 0u) != 0ull);
        if (!anyatt) {
            // common case: att token never spikes -> attn mask rows all zero
            if (lane < 32) {
                int t = lane >> 3, wd = lane & 7;
                AM[((long)t * G + g) * 8 + wd] = 0u;
            }
        } else {
            // rare: full k path (wave-uniform branch)
            float vk0 = 0.f, vk1 = 0.f, vk2 = 0.f, vk3 = 0.f;
            #pragma unroll
            for (int t = 0; t < 4; ++t) {
                float k0 = 0.f, k1 = 0.f, k2 = 0.f, k3 = 0.f;
                #pragma unroll
                for (int w = 0; w < 4; ++w) {
                    unsigned long long mm = m[t][w];
                    int cbase = w * 64;
                    while (mm) {
                        int b = __ffsll(mm) - 1;
                        mm &= (mm - 1);
                        const __hip_bfloat16* p = WkT + (cbase + b) * 256 + lane;
                        k0 += __bfloat162float(p[0]);
                        k1 += __bfloat162float(p[64]);
                        k2 += __bfloat162float(p[128]);
                        k3 += __bfloat162float(p[192]);
                    }
                }
                const float* pp = pos + t * 16384 + hw * 256 + lane;
                k0 += pp[0]; k1 += pp[64]; k2 += pp[128]; k3 += pp[192];

                vk0 = vk0 + (k0 - vk0) * 0.5f; bool t0 = (vk0 - 1.0f) >= 0.0f; if (t0) vk0 = 0.0f;
                vk1 = vk1 + (k1 - vk1) * 0.5f; bool t1 = (vk1 - 1.0f) >= 0.0f; if (t1) vk1 = 0.0f;
                vk2 = vk2 + (k2 - vk2) * 0.5f; bool t2 = (vk2 - 1.0f) >= 0.0f; if (t2) vk2 = 0.0f;
                vk3 = vk3 + (k3 - vk3) * 0.5f; bool t3 = (vk3 - 1.0f) >= 0.0f; if (t3) vk3 = 0.0f;

                bool x0  = t0 && ((attb >> (t * 4 + 0)) & 1u);
                bool x1  = t1 && ((attb >> (t * 4 + 1)) & 1u);
                bool x2b = t2 && ((attb >> (t * 4 + 2)) & 1u);
                bool x3  = t3 && ((attb >> (t * 4 + 3)) & 1u);
                unsigned long long bb0 = __ballot(x0);
                unsigned long long bb1 = __ballot(x1);
                unsigned long long bb2 = __ballot(x2b);
                unsigned long long bb3 = __ballot(x3);
                if (lane < 8) {
                    int i = lane >> 1;
                    unsigned long long sel = (i == 0) ? bb0 : (i == 1) ? bb1 : (i == 2) ? bb2 : bb3;
                    unsigned wdv = (lane & 1) ? (unsigned)(sel >> 32) : (unsigned)sel;
                    AM[((long)t * G + g) * 8 + lane] = wdv;
                }
            }
        }
    }
}

// ---------------- k3: outputs ----------------
// y[row,:] = bp + sum over set attn bits of Wp columns (usually just bp)
// attn_out = 0 identically (proved: v=(v+x)/2 < 1 for x in {0,1}, exact in fp32)
// Permutation verified: x2[t2,b2,hw2,nh*32+hd] = AM[(b2*4+(nh>>1))*64 + (nh&1)*32 + t2*8
//                       + (hw2>>3)] word (hw2&7), bit hd.
__global__ __launch_bounds__(256) void out_kernel(
    const unsigned* __restrict__ AM,
    const float* __restrict__ WpT,
    const float* __restrict__ bp,
    float* __restrict__ y,
    float* __restrict__ attn_out)
{
    int lane = threadIdx.x & 63;
    int wv   = threadIdx.x >> 6;
    int row  = blockIdx.x * 4 + wv;     // 0..262143 : (t2*65536 + b2*64 + hw2)
    int t2   = row >> 16;
    int b2   = (row >> 6) & 1023;
    int hw2  = row & 63;

    float4 acc = ((const float4*)bp)[lane];   // lane covers channels 4*lane..4*lane+3

    int nh   = lane >> 3;
    int srow = (b2 * 4 + (nh >> 1)) * 64 + (nh & 1) * 32 + t2 * 8 + (hw2 >> 3);
    unsigned W = AM[(long)srow * 8 + (hw2 & 7)];
    bool any = (__ballot(W != 0u) != 0ull);
    if (any) {
        #pragma unroll 1
        for (int n2 = 0; n2 < 8; ++n2) {
            unsigned Wn = __shfl(W, n2 * 8);
            while (Wn) {
                int hd = __ffs(Wn) - 1;
                Wn &= (Wn - 1);
                const float4* wp = (const float4*)(WpT + (n2 * 32 + hd) * 256);
                float4 wl = wp[lane];
                acc.x += wl.x; acc.y += wl.y; acc.z += wl.z; acc.w += wl.w;
            }
        }
    }
    ((float4*)y)[(long)row * 64 + lane] = acc;
    float4 z = make_float4(0.f, 0.f, 0.f, 0.f);
    ((float4*)attn_out)[(long)row * 64 + lane] = z;
}

extern "C" void kernel_launch(void* const* d_in, const int* in_sizes, int n_in,
                              void* d_out, int out_size, void* d_ws, size_t ws_size,
                              hipStream_t stream) {
    const float* x   = (const float*)d_in[0];
    const float* Wq  = (const float*)d_in[1];
    const float* Wk  = (const float*)d_in[2];
    const float* Wp  = (const float*)d_in[3];
    const float* bp  = (const float*)d_in[4];
    const float* pos = (const float*)d_in[5];

    float* y        = (float*)d_out;
    float* attn_out = y + 67108864L;    // second tuple element

    // workspace layout: XS masks 8 MB | AM masks 8 MB | WqT 128K | WkT 128K | WpT 256K
    char* ws = (char*)d_ws;
    unsigned long long* XS  = (unsigned long long*)(ws);
    unsigned*           AM  = (unsigned*)(ws + (8L << 20));
    __hip_bfloat16*     WqT = (__hip_bfloat16*)(ws + (16L << 20));
    __hip_bfloat16*     WkT = (__hip_bfloat16*)(ws + (16L << 20) + (128L << 10));
    float*              WpT = (float*)(ws + (16L << 20) + (256L << 10));

    prep_kernel<<<256, 256, 0, stream>>>(Wq, Wk, Wp, WqT, WkT, WpT);
    lif_x_kernel<<<65536, 256, 0, stream>>>(x, XS);
    qk_att_kernel<<<2048, 256, 0, stream>>>(XS, AM, WqT, WkT, pos);
    out_kernel<<<65536, 256, 0, stream>>>(AM, WpT, bp, y, attn_out);
}

// Round 2
// 864.387 us; speedup vs baseline: 1.0179x; 1.0179x over previous
//
#include <hip/hip_runtime.h>
#include <hip/hip_bf16.h>

// dims (fixed): T=4, B=1024, WH=WW=8, C=256, NH=8, HD=32
// tokens per timestep G = B*64 = 65536 ; plane = G*256 = 16777216 elements
static constexpr int  T4    = 4;
static constexpr int  G     = 65536;
static constexpr long PLANE = 16777216L;

__device__ __forceinline__ float bfh(unsigned short u) {
    union { unsigned u32; float f; } c; c.u32 = ((unsigned)u) << 16; return c.f;
}

// ---------------- prep: transposed weights into workspace ----------------
// WqT/WkT: bf16 [c][j] rows of 256 (512 B), WpT: f32 [c][j]
__global__ void prep_kernel(const float* __restrict__ Wq, const float* __restrict__ Wk,
                            const float* __restrict__ Wp,
                            __hip_bfloat16* __restrict__ WqT, __hip_bfloat16* __restrict__ WkT,
                            float* __restrict__ WpT)
{
    int c = blockIdx.x;      // 0..255 (input channel = row)
    int j = threadIdx.x;     // 0..255 (output channel = col)
    int idx = c * 256 + j;
    WqT[idx] = __float2bfloat16(Wq[j * 256 + c]);
    WkT[idx] = __float2bfloat16(Wk[j * 256 + c]);
    WpT[idx] = Wp[j * 256 + c];
}

// ---------------- fused: LIF(x) -> sparse q-GEMM -> LIF -> att -> AM masks ----
// Lane holds channels 4*lane..4*lane+3 (float4 x loads; ushort4 weight-row loads).
// Ballot word j: bit `lane` = spike of channel 4*lane+j.
// Att head i = lane>>3 (channels 32i..32i+31 = lanes 8i..8i+7, all j).
// Bit-exact LIF: v = v + (x - v)*0.5 (exact halving), spike = (v-1 >= 0), hard reset.
__global__ __launch_bounds__(256) void lif_qk_kernel(
    const float* __restrict__ x,
    unsigned* __restrict__ AM,
    const __hip_bfloat16* __restrict__ WqT,
    const __hip_bfloat16* __restrict__ WkT,
    const float* __restrict__ pos)
{
    int lane = threadIdx.x & 63;
    int wv   = threadIdx.x >> 6;
    int wid  = blockIdx.x * 4 + wv;       // 8192 waves total
    int sh   = (lane & 56);               // 8*(lane>>3): byte shift for this lane's head

    for (int gi = 0; gi < 8; ++gi) {
        int g  = wid * 8 + gi;            // token 0..65535
        int hw = g & 63;

        // preload all 4 timesteps of this token's 4 channels
        float4 X[4];
        #pragma unroll
        for (int t = 0; t < 4; ++t)
            X[t] = ((const float4*)(x + (long)t * PLANE + (long)g * 256))[lane];

        unsigned long long sm[4][4];      // spike masks per t per word j
        float4 v  = make_float4(0.f, 0.f, 0.f, 0.f);   // input LIF state
        float4 vq = make_float4(0.f, 0.f, 0.f, 0.f);   // q LIF state
        float  va = 0.f;                                // att LIF state (this lane's head)
        unsigned attb = 0u;                             // bit t = att spike of lane's head

        #pragma unroll
        for (int t = 0; t < 4; ++t) {
            // input LIF on lane's 4 channels
            v.x = v.x + (X[t].x - v.x) * 0.5f; bool s0 = (v.x - 1.0f) >= 0.0f; if (s0) v.x = 0.f;
            v.y = v.y + (X[t].y - v.y) * 0.5f; bool s1 = (v.y - 1.0f) >= 0.0f; if (s1) v.y = 0.f;
            v.z = v.z + (X[t].z - v.z) * 0.5f; bool s2 = (v.z - 1.0f) >= 0.0f; if (s2) v.z = 0.f;
            v.w = v.w + (X[t].w - v.w) * 0.5f; bool s3 = (v.w - 1.0f) >= 0.0f; if (s3) v.w = 0.f;
            sm[t][0] = __ballot(s0);
            sm[t][1] = __ballot(s1);
            sm[t][2] = __ballot(s2);
            sm[t][3] = __ballot(s3);

            // sparse q row-gather: one ushort4 (8B) load per set bit
            float q0 = 0.f, q1 = 0.f, q2 = 0.f, q3 = 0.f;
            #pragma unroll
            for (int j = 0; j < 4; ++j) {
                unsigned long long mm = sm[t][j];
                while (mm) {
                    int b = __ffsll(mm) - 1;
                    mm &= (mm - 1);
                    int c = 4 * b + j;
                    ushort4 w = *((const ushort4*)(WqT + c * 256 + 4 * lane));
                    q0 += bfh(w.x); q1 += bfh(w.y); q2 += bfh(w.z); q3 += bfh(w.w);
                }
            }

            // q LIF
            vq.x = vq.x + (q0 - vq.x) * 0.5f; bool t0 = (vq.x - 1.0f) >= 0.0f; if (t0) vq.x = 0.f;
            vq.y = vq.y + (q1 - vq.y) * 0.5f; bool t1 = (vq.y - 1.0f) >= 0.0f; if (t1) vq.y = 0.f;
            vq.z = vq.z + (q2 - vq.z) * 0.5f; bool t2 = (vq.z - 1.0f) >= 0.0f; if (t2) vq.z = 0.f;
            vq.w = vq.w + (q3 - vq.w) * 0.5f; bool t3 = (vq.w - 1.0f) >= 0.0f; if (t3) vq.w = 0.f;
            unsigned long long qb0 = __ballot(t0);
            unsigned long long qb1 = __ballot(t1);
            unsigned long long qb2 = __ballot(t2);
            unsigned long long qb3 = __ballot(t3);

            // att token: integer popcount over this lane's head (32 channels)
            int cnt = __popc((unsigned)((qb0 >> sh) & 0xFFull))
                    + __popc((unsigned)((qb1 >> sh) & 0xFFull))
                    + __popc((unsigned)((qb2 >> sh) & 0xFFull))
                    + __popc((unsigned)((qb3 >> sh) & 0xFFull));
            va = va + ((float)cnt - va) * 0.5f;
            bool a = (va - 1.0f) >= 0.0f; if (a) va = 0.f;
            attb |= (a ? 1u : 0u) << t;
        }

        bool anyatt = (__ballot(attb != 0u) != 0ull);
        if (!anyatt) {
            // common case: att never spikes anywhere -> all-zero attn masks
            if (lane < 32) {
                int t = lane >> 3, wd = lane & 7;
                AM[((long)t * G + g) * 8 + wd] = 0u;
            }
        } else {
            // rare: full k path (wave-uniform branch)
            float4 vk = make_float4(0.f, 0.f, 0.f, 0.f);
            #pragma unroll
            for (int t = 0; t < 4; ++t) {
                float k0 = 0.f, k1 = 0.f, k2 = 0.f, k3 = 0.f;
                #pragma unroll
                for (int j = 0; j < 4; ++j) {
                    unsigned long long mm = sm[t][j];
                    while (mm) {
                        int b = __ffsll(mm) - 1;
                        mm &= (mm - 1);
                        int c = 4 * b + j;
                        ushort4 w = *((const ushort4*)(WkT + c * 256 + 4 * lane));
                        k0 += bfh(w.x); k1 += bfh(w.y); k2 += bfh(w.z); k3 += bfh(w.w);
                    }
                }
                float4 pp = ((const float4*)(pos + t * 16384 + hw * 256))[lane];
                k0 += pp.x; k1 += pp.y; k2 += pp.z; k3 += pp.w;

                vk.x = vk.x + (k0 - vk.x) * 0.5f; bool t0 = (vk.x - 1.0f) >= 0.0f; if (t0) vk.x = 0.f;
                vk.y = vk.y + (k1 - vk.y) * 0.5f; bool t1 = (vk.y - 1.0f) >= 0.0f; if (t1) vk.y = 0.f;
                vk.z = vk.z + (k2 - vk.z) * 0.5f; bool t2 = (vk.z - 1.0f) >= 0.0f; if (t2) vk.z = 0.f;
                vk.w = vk.w + (k3 - vk.w) * 0.5f; bool t3 = (vk.w - 1.0f) >= 0.0f; if (t3) vk.w = 0.f;

                bool at = ((attb >> t) & 1u) != 0u;   // lane's head att gate
                unsigned long long bb[4];
                bb[0] = __ballot(t0 && at);
                bb[1] = __ballot(t1 && at);
                bb[2] = __ballot(t2 && at);
                bb[3] = __ballot(t3 && at);
                // assemble AM word for head n2=lane (lanes 0..7):
                // bit hd = channel 32*n2+hd = ballot word (hd&3), bit (8*n2 + (hd>>2))
                if (lane < 8) {
                    unsigned wdv = 0u;
                    #pragma unroll
                    for (int hd = 0; hd < 32; ++hd) {
                        int ls = lane * 8 + (hd >> 2);
                        wdv |= (unsigned)((bb[hd & 3] >> ls) & 1ull) << hd;
                    }
                    AM[((long)t * G + g) * 8 + lane] = wdv;
                }
            }
        }
    }
}

// ---------------- out: y = bp (+ rare Wp columns), attn_out = 0 ----------------
// attn_out ≡ 0 proved: x2 in {0,1}, v'=(v+x)/2 < 1 strictly (exact dyadic fp32).
// Permutation (verified R0): x2[t2,b2,hw2,nh*32+hd] = AM[(b2*4+(nh>>1))*64
//   + (nh&1)*32 + t2*8 + (hw2>>3)] word (hw2&7), bit hd.
__global__ __launch_bounds__(256) void out_kernel(
    const unsigned* __restrict__ AM,
    const float* __restrict__ WpT,
    const float* __restrict__ bp,
    float* __restrict__ y,
    float* __restrict__ attn_out)
{
    int lane = threadIdx.x & 63;
    int wv   = threadIdx.x >> 6;
    int row  = blockIdx.x * 4 + wv;     // 0..262143 : (t2*65536 + b2*64 + hw2)
    int t2   = row >> 16;
    int b2   = (row >> 6) & 1023;
    int hw2  = row & 63;

    float4 acc = ((const float4*)bp)[lane];   // channels 4*lane..4*lane+3

    int nh   = lane >> 3;
    int srow = (b2 * 4 + (nh >> 1)) * 64 + (nh & 1) * 32 + t2 * 8 + (hw2 >> 3);
    unsigned W = AM[(long)srow * 8 + (hw2 & 7)];
    bool any = (__ballot(W != 0u) != 0ull);
    if (any) {
        #pragma unroll 1
        for (int n2 = 0; n2 < 8; ++n2) {
            unsigned Wn = __shfl(W, n2 * 8);
            while (Wn) {
                int hd = __ffs(Wn) - 1;
                Wn &= (Wn - 1);
                const float4* wp = (const float4*)(WpT + (n2 * 32 + hd) * 256);
                float4 wl = wp[lane];
                acc.x += wl.x; acc.y += wl.y; acc.z += wl.z; acc.w += wl.w;
            }
        }
    }
    ((float4*)y)[(long)row * 64 + lane] = acc;
    float4 z = make_float4(0.f, 0.f, 0.f, 0.f);
    ((float4*)attn_out)[(long)row * 64 + lane] = z;
}

extern "C" void kernel_launch(void* const* d_in, const int* in_sizes, int n_in,
                              void* d_out, int out_size, void* d_ws, size_t ws_size,
                              hipStream_t stream) {
    const float* x   = (const float*)d_in[0];
    const float* Wq  = (const float*)d_in[1];
    const float* Wk  = (const float*)d_in[2];
    const float* Wp  = (const float*)d_in[3];
    const float* bp  = (const float*)d_in[4];
    const float* pos = (const float*)d_in[5];

    float* y        = (float*)d_out;
    float* attn_out = y + 67108864L;    // second tuple element

    // workspace layout: AM masks 8 MB | WqT 128K | WkT 128K | WpT 256K
    char* ws = (char*)d_ws;
    unsigned*           AM  = (unsigned*)(ws);
    __hip_bfloat16*     WqT = (__hip_bfloat16*)(ws + (8L << 20));
    __hip_bfloat16*     WkT = (__hip_bfloat16*)(ws + (8L << 20) + (128L << 10));
    float*              WpT = (float*)(ws + (8L << 20) + (256L << 10));

    prep_kernel<<<256, 256, 0, stream>>>(Wq, Wk, Wp, WqT, WkT, WpT);
    lif_qk_kernel<<<2048, 256, 0, stream>>>(x, AM, WqT, WkT, pos);
    out_kernel<<<65536, 256, 0, stream>>>(AM, WpT, bp, y, attn_out);
}

// Round 3
// 806.971 us; speedup vs baseline: 1.0904x; 1.0712x over previous
//
#include <hip/hip_runtime.h>
#include <hip/hip_bf16.h>

// dims (fixed): T=4, B=1024, WH=WW=8, C=256, NH=8, HD=32
// tokens per timestep G = B*64 = 65536 ; plane = G*256 = 16777216 elements
static constexpr int  T4    = 4;
static constexpr int  G     = 65536;
static constexpr long PLANE = 16777216L;

__device__ __forceinline__ float bfh(unsigned short u) {
    union { unsigned u32; float f; } c; c.u32 = ((unsigned)u) << 16; return c.f;
}

// ---------------- prep: transposed weights into workspace ----------------
__global__ void prep_kernel(const float* __restrict__ Wq, const float* __restrict__ Wk,
                            const float* __restrict__ Wp,
                            __hip_bfloat16* __restrict__ WqT, __hip_bfloat16* __restrict__ WkT,
                            float* __restrict__ WpT)
{
    int c = blockIdx.x;      // input channel (row of transposed)
    int j = threadIdx.x;     // output channel
    int idx = c * 256 + j;
    WqT[idx] = __float2bfloat16(Wq[j * 256 + c]);
    WkT[idx] = __float2bfloat16(Wk[j * 256 + c]);
    WpT[idx] = Wp[j * 256 + c];
}

// depth-2 pipelined sparse row-gather over one 64-bit mask word
__device__ __forceinline__ void gather_word(unsigned long long mm, int j, int lane,
                                            const __hip_bfloat16* __restrict__ WT,
                                            float& q0, float& q1, float& q2, float& q3)
{
    if (!mm) return;
    int b = __ffsll(mm) - 1; mm &= (mm - 1);
    ushort4 w = *((const ushort4*)(WT + (4 * b + j) * 256 + 4 * lane));
    while (mm) {
        int b2 = __ffsll(mm) - 1; mm &= (mm - 1);
        ushort4 w2 = *((const ushort4*)(WT + (4 * b2 + j) * 256 + 4 * lane));  // in flight
        q0 += bfh(w.x); q1 += bfh(w.y); q2 += bfh(w.z); q3 += bfh(w.w);
        w = w2;
    }
    q0 += bfh(w.x); q1 += bfh(w.y); q2 += bfh(w.z); q3 += bfh(w.w);
}

// ---------------- fused: LIF(x) -> sparse q-GEMM -> LIF -> att -> AM masks ----
// Lane holds channels 4*lane..4*lane+3. Ballot word j bit lane = spike(4*lane+j).
// Bit-exact LIF: v = v + (x-v)*0.5, spike = (v-1 >= 0), hard reset.
__global__ __launch_bounds__(256) void lif_qk_kernel(
    const float* __restrict__ x,
    unsigned* __restrict__ AM,
    const __hip_bfloat16* __restrict__ WqT,
    const __hip_bfloat16* __restrict__ WkT,
    const float* __restrict__ pos)
{
    int lane = threadIdx.x & 63;
    int wv   = threadIdx.x >> 6;
    int wid  = blockIdx.x * 4 + wv;       // 16384 waves
    int sh   = (lane & 56);               // 8*(lane>>3)

    for (int gi = 0; gi < 4; ++gi) {
        int g  = wid * 4 + gi;            // token 0..65535
        int hw = g & 63;

        float4 X[4];
        #pragma unroll
        for (int t = 0; t < 4; ++t)
            X[t] = ((const float4*)(x + (long)t * PLANE + (long)g * 256))[lane];

        unsigned long long sm[4][4];
        float4 v  = make_float4(0.f, 0.f, 0.f, 0.f);
        float4 vq = make_float4(0.f, 0.f, 0.f, 0.f);
        float  va = 0.f;
        unsigned attb = 0u;

        #pragma unroll
        for (int t = 0; t < 4; ++t) {
            v.x = v.x + (X[t].x - v.x) * 0.5f; bool s0 = (v.x - 1.0f) >= 0.0f; if (s0) v.x = 0.f;
            v.y = v.y + (X[t].y - v.y) * 0.5f; bool s1 = (v.y - 1.0f) >= 0.0f; if (s1) v.y = 0.f;
            v.z = v.z + (X[t].z - v.z) * 0.5f; bool s2 = (v.z - 1.0f) >= 0.0f; if (s2) v.z = 0.f;
            v.w = v.w + (X[t].w - v.w) * 0.5f; bool s3 = (v.w - 1.0f) >= 0.0f; if (s3) v.w = 0.f;
            sm[t][0] = __ballot(s0);
            sm[t][1] = __ballot(s1);
            sm[t][2] = __ballot(s2);
            sm[t][3] = __ballot(s3);

            float q0 = 0.f, q1 = 0.f, q2 = 0.f, q3 = 0.f;
            #pragma unroll
            for (int j = 0; j < 4; ++j)
                gather_word(sm[t][j], j, lane, WqT, q0, q1, q2, q3);

            vq.x = vq.x + (q0 - vq.x) * 0.5f; bool t0 = (vq.x - 1.0f) >= 0.0f; if (t0) vq.x = 0.f;
            vq.y = vq.y + (q1 - vq.y) * 0.5f; bool t1 = (vq.y - 1.0f) >= 0.0f; if (t1) vq.y = 0.f;
            vq.z = vq.z + (q2 - vq.z) * 0.5f; bool t2 = (vq.z - 1.0f) >= 0.0f; if (t2) vq.z = 0.f;
            vq.w = vq.w + (q3 - vq.w) * 0.5f; bool t3 = (vq.w - 1.0f) >= 0.0f; if (t3) vq.w = 0.f;
            unsigned long long qb0 = __ballot(t0);
            unsigned long long qb1 = __ballot(t1);
            unsigned long long qb2 = __ballot(t2);
            unsigned long long qb3 = __ballot(t3);

            int cnt = __popc((unsigned)((qb0 >> sh) & 0xFFull))
                    + __popc((unsigned)((qb1 >> sh) & 0xFFull))
                    + __popc((unsigned)((qb2 >> sh) & 0xFFull))
                    + __popc((unsigned)((qb3 >> sh) & 0xFFull));
            va = va + ((float)cnt - va) * 0.5f;
            bool a = (va - 1.0f) >= 0.0f; if (a) va = 0.f;
            attb |= (a ? 1u : 0u) << t;
        }

        bool anyatt = (__ballot(attb != 0u) != 0ull);
        if (!anyatt) {
            if (lane < 32) {
                int t = lane >> 3, wd = lane & 7;
                AM[((long)t * G + g) * 8 + wd] = 0u;
            }
        } else {
            // rare: full k path (wave-uniform)
            float4 vk = make_float4(0.f, 0.f, 0.f, 0.f);
            #pragma unroll
            for (int t = 0; t < 4; ++t) {
                float k0 = 0.f, k1 = 0.f, k2 = 0.f, k3 = 0.f;
                #pragma unroll
                for (int j = 0; j < 4; ++j)
                    gather_word(sm[t][j], j, lane, WkT, k0, k1, k2, k3);
                float4 pp = ((const float4*)(pos + t * 16384 + hw * 256))[lane];
                k0 += pp.x; k1 += pp.y; k2 += pp.z; k3 += pp.w;

                vk.x = vk.x + (k0 - vk.x) * 0.5f; bool t0 = (vk.x - 1.0f) >= 0.0f; if (t0) vk.x = 0.f;
                vk.y = vk.y + (k1 - vk.y) * 0.5f; bool t1 = (vk.y - 1.0f) >= 0.0f; if (t1) vk.y = 0.f;
                vk.z = vk.z + (k2 - vk.z) * 0.5f; bool t2 = (vk.z - 1.0f) >= 0.0f; if (t2) vk.z = 0.f;
                vk.w = vk.w + (k3 - vk.w) * 0.5f; bool t3 = (vk.w - 1.0f) >= 0.0f; if (t3) vk.w = 0.f;

                bool at = ((attb >> t) & 1u) != 0u;
                unsigned long long bb[4];
                bb[0] = __ballot(t0 && at);
                bb[1] = __ballot(t1 && at);
                bb[2] = __ballot(t2 && at);
                bb[3] = __ballot(t3 && at);
                if (lane < 8) {
                    unsigned wdv = 0u;
                    #pragma unroll
                    for (int hd = 0; hd < 32; ++hd) {
                        int ls = lane * 8 + (hd >> 2);
                        wdv |= (unsigned)((bb[hd & 3] >> ls) & 1ull) << hd;
                    }
                    AM[((long)t * G + g) * 8 + lane] = wdv;
                }
            }
        }
    }
}

// ---------------- out: fat waves, streaming stores ----------------
// y[row,:] = bp (+ rare Wp columns); attn_out = 0 identically (proof: x2 in {0,1},
// v'=(v+x)/2 < 1 strictly, exact dyadic fp32 -> never spikes, independent of AM).
// AM word for next row prefetched so the (rare) branch never stalls the store stream.
__global__ __launch_bounds__(256) void out_kernel(
    const unsigned* __restrict__ AM,
    const float* __restrict__ WpT,
    const float* __restrict__ bp,
    float* __restrict__ y,
    float* __restrict__ attn_out)
{
    int lane = threadIdx.x & 63;
    int wv   = threadIdx.x >> 6;
    long wave = (long)blockIdx.x * 4 + wv;      // 0..8191
    int  nh   = lane >> 3;

    float4 base = ((const float4*)bp)[lane];
    const float4 z = make_float4(0.f, 0.f, 0.f, 0.f);

    long row0 = wave * 32;                      // 32 consecutive rows per wave
    // prefetch AM word for first row
    {
        // nothing
    }
    int t2  = (int)(row0 >> 16);
    int b2  = (int)(row0 >> 6) & 1023;
    int hw2 = (int)row0 & 63;
    int srow = (b2 * 4 + (nh >> 1)) * 64 + (nh & 1) * 32 + t2 * 8 + (hw2 >> 3);
    unsigned W = AM[(long)srow * 8 + (hw2 & 7)];

    for (int r = 0; r < 32; ++r) {
        long row = row0 + r;
        unsigned Wn = 0u;
        if (r < 31) {
            long rown = row + 1;
            int t2n  = (int)(rown >> 16);
            int b2n  = (int)(rown >> 6) & 1023;
            int hw2n = (int)rown & 63;
            int srn  = (b2n * 4 + (nh >> 1)) * 64 + (nh & 1) * 32 + t2n * 8 + (hw2n >> 3);
            Wn = AM[(long)srn * 8 + (hw2n & 7)];
        }

        float4 val = base;
        if (__ballot(W != 0u) != 0ull) {        // essentially never taken
            #pragma unroll 1
            for (int n2 = 0; n2 < 8; ++n2) {
                unsigned Wx = __shfl(W, n2 * 8);
                while (Wx) {
                    int hd = __ffs(Wx) - 1;
                    Wx &= (Wx - 1);
                    float4 wl = ((const float4*)(WpT + (n2 * 32 + hd) * 256))[lane];
                    val.x += wl.x; val.y += wl.y; val.z += wl.z; val.w += wl.w;
                }
            }
        }
        ((float4*)y)[row * 64 + lane]        = val;
        ((float4*)attn_out)[row * 64 + lane] = z;
        W = Wn;
    }
}

extern "C" void kernel_launch(void* const* d_in, const int* in_sizes, int n_in,
                              void* d_out, int out_size, void* d_ws, size_t ws_size,
                              hipStream_t stream) {
    const float* x   = (const float*)d_in[0];
    const float* Wq  = (const float*)d_in[1];
    const float* Wk  = (const float*)d_in[2];
    const float* Wp  = (const float*)d_in[3];
    const float* bp  = (const float*)d_in[4];
    const float* pos = (const float*)d_in[5];

    float* y        = (float*)d_out;
    float* attn_out = y + 67108864L;

    char* ws = (char*)d_ws;
    unsigned*           AM  = (unsigned*)(ws);
    __hip_bfloat16*     WqT = (__hip_bfloat16*)(ws + (8L << 20));
    __hip_bfloat16*     WkT = (__hip_bfloat16*)(ws + (8L << 20) + (128L << 10));
    float*              WpT = (float*)(ws + (8L << 20) + (256L << 10));

    prep_kernel<<<256, 256, 0, stream>>>(Wq, Wk, Wp, WqT, WkT, WpT);
    lif_qk_kernel<<<4096, 256, 0, stream>>>(x, AM, WqT, WkT, pos);
    out_kernel<<<2048, 256, 0, stream>>>(AM, WpT, bp, y, attn_out);
}

// Round 4
// 788.939 us; speedup vs baseline: 1.1153x; 1.0229x over previous
//
#include <hip/hip_runtime.h>
#include <hip/hip_bf16.h>

// dims (fixed): T=4, B=1024, WH=WW=8, C=256, NH=8, HD=32
// tokens per timestep G = B*64 = 65536 ; plane = G*256 = 16777216 elements
static constexpr int  G     = 65536;
static constexpr long PLANE = 16777216L;

__device__ __forceinline__ float bfh(unsigned short u) {
    union { unsigned u32; float f; } c; c.u32 = ((unsigned)u) << 16; return c.f;
}

// ---------------- prep: transposed weights into workspace + flag clear --------
__global__ void prep_kernel(const float* __restrict__ Wq, const float* __restrict__ Wk,
                            const float* __restrict__ Wp,
                            __hip_bfloat16* __restrict__ WqT, __hip_bfloat16* __restrict__ WkT,
                            float* __restrict__ WpT, unsigned* __restrict__ flag)
{
    int c = blockIdx.x;      // input channel (row of transposed)
    int j = threadIdx.x;     // output channel
    int idx = c * 256 + j;
    WqT[idx] = __float2bfloat16(Wq[j * 256 + c]);
    WkT[idx] = __float2bfloat16(Wk[j * 256 + c]);
    WpT[idx] = Wp[j * 256 + c];
    if (c == 0 && j == 0) *flag = 0u;
}

// depth-2 pipelined sparse row-gather over one 64-bit mask word (rare k-path)
__device__ __forceinline__ void gather_word(unsigned long long mm, int j, int lane,
                                            const __hip_bfloat16* __restrict__ WT,
                                            float& q0, float& q1, float& q2, float& q3)
{
    if (!mm) return;
    int b = __ffsll(mm) - 1; mm &= (mm - 1);
    ushort4 w = *((const ushort4*)(WT + (4 * b + j) * 256 + 4 * lane));
    while (mm) {
        int b2 = __ffsll(mm) - 1; mm &= (mm - 1);
        ushort4 w2 = *((const ushort4*)(WT + (4 * b2 + j) * 256 + 4 * lane));
        q0 += bfh(w.x); q1 += bfh(w.y); q2 += bfh(w.z); q3 += bfh(w.w);
        w = w2;
    }
    q0 += bfh(w.x); q1 += bfh(w.y); q2 += bfh(w.z); q3 += bfh(w.w);
}

// 8 independent chains (2 timesteps x 4 words): up to 8 loads in flight/iter.
// Masks are wave-uniform (ballot results) -> guards are cheap scalar branches.
__device__ __forceinline__ void gather8(
    unsigned long long m0, unsigned long long m1, unsigned long long m2, unsigned long long m3,
    unsigned long long n0, unsigned long long n1, unsigned long long n2, unsigned long long n3,
    const __hip_bfloat16* __restrict__ WT, int lane,
    float4& qa, float4& qb)
{
    const __hip_bfloat16* base = WT + 4 * lane;
    ushort4 w0 = {0,0,0,0}, w1 = {0,0,0,0}, w2 = {0,0,0,0}, w3 = {0,0,0,0};
    ushort4 x0 = {0,0,0,0}, x1 = {0,0,0,0}, x2 = {0,0,0,0}, x3 = {0,0,0,0};
    while (m0 | m1 | m2 | m3 | n0 | n1 | n2 | n3) {
        bool h0 = m0 != 0, h1 = m1 != 0, h2 = m2 != 0, h3 = m3 != 0;
        bool g0 = n0 != 0, g1 = n1 != 0, g2 = n2 != 0, g3 = n3 != 0;
        if (h0) { int b = __ffsll(m0) - 1; m0 &= m0 - 1; w0 = *(const ushort4*)(base + (4*b+0)*256); }
        if (h1) { int b = __ffsll(m1) - 1; m1 &= m1 - 1; w1 = *(const ushort4*)(base + (4*b+1)*256); }
        if (h2) { int b = __ffsll(m2) - 1; m2 &= m2 - 1; w2 = *(const ushort4*)(base + (4*b+2)*256); }
        if (h3) { int b = __ffsll(m3) - 1; m3 &= m3 - 1; w3 = *(const ushort4*)(base + (4*b+3)*256); }
        if (g0) { int b = __ffsll(n0) - 1; n0 &= n0 - 1; x0 = *(const ushort4*)(base + (4*b+0)*256); }
        if (g1) { int b = __ffsll(n1) - 1; n1 &= n1 - 1; x1 = *(const ushort4*)(base + (4*b+1)*256); }
        if (g2) { int b = __ffsll(n2) - 1; n2 &= n2 - 1; x2 = *(const ushort4*)(base + (4*b+2)*256); }
        if (g3) { int b = __ffsll(n3) - 1; n3 &= n3 - 1; x3 = *(const ushort4*)(base + (4*b+3)*256); }
        if (h0) { qa.x += bfh(w0.x); qa.y += bfh(w0.y); qa.z += bfh(w0.z); qa.w += bfh(w0.w); }
        if (h1) { qa.x += bfh(w1.x); qa.y += bfh(w1.y); qa.z += bfh(w1.z); qa.w += bfh(w1.w); }
        if (h2) { qa.x += bfh(w2.x); qa.y += bfh(w2.y); qa.z += bfh(w2.z); qa.w += bfh(w2.w); }
        if (h3) { qa.x += bfh(w3.x); qa.y += bfh(w3.y); qa.z += bfh(w3.z); qa.w += bfh(w3.w); }
        if (g0) { qb.x += bfh(x0.x); qb.y += bfh(x0.y); qb.z += bfh(x0.z); qb.w += bfh(x0.w); }
        if (g1) { qb.x += bfh(x1.x); qb.y += bfh(x1.y); qb.z += bfh(x1.z); qb.w += bfh(x1.w); }
        if (g2) { qb.x += bfh(x2.x); qb.y += bfh(x2.y); qb.z += bfh(x2.z); qb.w += bfh(x2.w); }
        if (g3) { qb.x += bfh(x3.x); qb.y += bfh(x3.y); qb.z += bfh(x3.z); qb.w += bfh(x3.w); }
    }
}

// ---------------- fused: LIF(x) -> sparse q-GEMM -> LIF -> att -> AM masks ----
// Lane holds channels 4*lane..4*lane+3. Ballot word j bit lane = spike(4*lane+j).
// Bit-exact LIF: v = v + (x-v)*0.5, spike = (v-1 >= 0), hard reset.
__global__ __launch_bounds__(256) void lif_qk_kernel(
    const float* __restrict__ x,
    unsigned* __restrict__ AM,
    const __hip_bfloat16* __restrict__ WqT,
    const __hip_bfloat16* __restrict__ WkT,
    const float* __restrict__ pos,
    unsigned* __restrict__ flag)
{
    int lane = threadIdx.x & 63;
    int wv   = threadIdx.x >> 6;
    int wid  = blockIdx.x * 4 + wv;       // 16384 waves
    int sh   = (lane & 56);               // 8*(lane>>3)

    for (int gi = 0; gi < 4; ++gi) {
        int g  = wid * 4 + gi;            // token 0..65535
        int hw = g & 63;

        float4 X[4];
        #pragma unroll
        for (int t = 0; t < 4; ++t)
            X[t] = ((const float4*)(x + (long)t * PLANE + (long)g * 256))[lane];

        // phase 1: all 16 input-spike mask words (pure VALU + ballots)
        unsigned long long sm[4][4];
        float4 v = make_float4(0.f, 0.f, 0.f, 0.f);
        #pragma unroll
        for (int t = 0; t < 4; ++t) {
            v.x = v.x + (X[t].x - v.x) * 0.5f; bool s0 = (v.x - 1.0f) >= 0.0f; if (s0) v.x = 0.f;
            v.y = v.y + (X[t].y - v.y) * 0.5f; bool s1 = (v.y - 1.0f) >= 0.0f; if (s1) v.y = 0.f;
            v.z = v.z + (X[t].z - v.z) * 0.5f; bool s2 = (v.z - 1.0f) >= 0.0f; if (s2) v.z = 0.f;
            v.w = v.w + (X[t].w - v.w) * 0.5f; bool s3 = (v.w - 1.0f) >= 0.0f; if (s3) v.w = 0.f;
            sm[t][0] = __ballot(s0);
            sm[t][1] = __ballot(s1);
            sm[t][2] = __ballot(s2);
            sm[t][3] = __ballot(s3);
        }

        // phase 2: sparse q gathers, 8 chains in flight
        float4 qs0 = make_float4(0.f,0.f,0.f,0.f), qs1 = make_float4(0.f,0.f,0.f,0.f);
        float4 qs2 = make_float4(0.f,0.f,0.f,0.f), qs3 = make_float4(0.f,0.f,0.f,0.f);
        gather8(sm[0][0], sm[0][1], sm[0][2], sm[0][3],
                sm[1][0], sm[1][1], sm[1][2], sm[1][3], WqT, lane, qs0, qs1);
        gather8(sm[2][0], sm[2][1], sm[2][2], sm[2][3],
                sm[3][0], sm[3][1], sm[3][2], sm[3][3], WqT, lane, qs2, qs3);

        // phase 3: q LIF + att-token LIF (identical arithmetic to prior rounds)
        float4 vq = make_float4(0.f, 0.f, 0.f, 0.f);
        float  va = 0.f;
        unsigned attb = 0u;
        #pragma unroll
        for (int t = 0; t < 4; ++t) {
            float4 q = (t == 0) ? qs0 : (t == 1) ? qs1 : (t == 2) ? qs2 : qs3;
            vq.x = vq.x + (q.x - vq.x) * 0.5f; bool t0 = (vq.x - 1.0f) >= 0.0f; if (t0) vq.x = 0.f;
            vq.y = vq.y + (q.y - vq.y) * 0.5f; bool t1 = (vq.y - 1.0f) >= 0.0f; if (t1) vq.y = 0.f;
            vq.z = vq.z + (q.z - vq.z) * 0.5f; bool t2 = (vq.z - 1.0f) >= 0.0f; if (t2) vq.z = 0.f;
            vq.w = vq.w + (q.w - vq.w) * 0.5f; bool t3 = (vq.w - 1.0f) >= 0.0f; if (t3) vq.w = 0.f;
            unsigned long long qb0 = __ballot(t0);
            unsigned long long qb1 = __ballot(t1);
            unsigned long long qb2 = __ballot(t2);
            unsigned long long qb3 = __ballot(t3);

            int cnt = __popc((unsigned)((qb0 >> sh) & 0xFFull))
                    + __popc((unsigned)((qb1 >> sh) & 0xFFull))
                    + __popc((unsigned)((qb2 >> sh) & 0xFFull))
                    + __popc((unsigned)((qb3 >> sh) & 0xFFull));
            va = va + ((float)cnt - va) * 0.5f;
            bool a = (va - 1.0f) >= 0.0f; if (a) va = 0.f;
            attb |= (a ? 1u : 0u) << t;
        }

        bool anyatt = (__ballot(attb != 0u) != 0ull);
        if (!anyatt) {
            if (lane < 32) {
                int t = lane >> 3, wd = lane & 7;
                AM[((long)t * G + g) * 8 + wd] = 0u;
            }
        } else {
            // rare: full k path (wave-uniform)
            if (lane == 0) atomicOr(flag, 1u);
            float4 vk = make_float4(0.f, 0.f, 0.f, 0.f);
            #pragma unroll
            for (int t = 0; t < 4; ++t) {
                float k0 = 0.f, k1 = 0.f, k2 = 0.f, k3 = 0.f;
                #pragma unroll
                for (int j = 0; j < 4; ++j)
                    gather_word(sm[t][j], j, lane, WkT, k0, k1, k2, k3);
                float4 pp = ((const float4*)(pos + t * 16384 + hw * 256))[lane];
                k0 += pp.x; k1 += pp.y; k2 += pp.z; k3 += pp.w;

                vk.x = vk.x + (k0 - vk.x) * 0.5f; bool t0 = (vk.x - 1.0f) >= 0.0f; if (t0) vk.x = 0.f;
                vk.y = vk.y + (k1 - vk.y) * 0.5f; bool t1 = (vk.y - 1.0f) >= 0.0f; if (t1) vk.y = 0.f;
                vk.z = vk.z + (k2 - vk.z) * 0.5f; bool t2 = (vk.z - 1.0f) >= 0.0f; if (t2) vk.z = 0.f;
                vk.w = vk.w + (k3 - vk.w) * 0.5f; bool t3 = (vk.w - 1.0f) >= 0.0f; if (t3) vk.w = 0.f;

                bool at = ((attb >> t) & 1u) != 0u;
                unsigned long long bb[4];
                bb[0] = __ballot(t0 && at);
                bb[1] = __ballot(t1 && at);
                bb[2] = __ballot(t2 && at);
                bb[3] = __ballot(t3 && at);
                if (lane < 8) {
                    unsigned wdv = 0u;
                    #pragma unroll
                    for (int hd = 0; hd < 32; ++hd) {
                        int ls = lane * 8 + (hd >> 2);
                        wdv |= (unsigned)((bb[hd & 3] >> ls) & 1ull) << hd;
                    }
                    AM[((long)t * G + g) * 8 + lane] = wdv;
                }
            }
        }
    }
}

// ---------------- out: flag-gated pure streaming stores ----------------
// Common case (flag==0): y = bp broadcast, attn_out = 0; no loads in the loop.
// attn_out ≡ 0 proved: x2 in {0,1}, v'=(v+x)/2 < 1 strictly (exact dyadic fp32).
// Rare case: per-row AM gather (permutation verified R0).
__global__ __launch_bounds__(256) void out_kernel(
    const unsigned* __restrict__ AM,
    const float* __restrict__ WpT,
    const float* __restrict__ bp,
    const unsigned* __restrict__ flag,
    float* __restrict__ y,
    float* __restrict__ attn_out)
{
    int lane = threadIdx.x & 63;
    int wv   = threadIdx.x >> 6;
    long wave = (long)blockIdx.x * 4 + wv;      // 0..8191 ; 32 rows/wave
    int  nh   = lane >> 3;

    float4 base = ((const float4*)bp)[lane];
    const float4 z = make_float4(0.f, 0.f, 0.f, 0.f);
    long row0 = wave * 32;

    if (*flag == 0u) {
        float4* yp = (float4*)y        + row0 * 64 + lane;
        float4* ap = (float4*)attn_out + row0 * 64 + lane;
        #pragma unroll 8
        for (int r = 0; r < 32; ++r) yp[r * 64] = base;
        #pragma unroll 8
        for (int r = 0; r < 32; ++r) ap[r * 64] = z;
        return;
    }

    // rare path
    int t2  = (int)(row0 >> 16);
    int b2  = (int)(row0 >> 6) & 1023;
    int hw2 = (int)row0 & 63;
    int srow = (b2 * 4 + (nh >> 1)) * 64 + (nh & 1) * 32 + t2 * 8 + (hw2 >> 3);
    unsigned W = AM[(long)srow * 8 + (hw2 & 7)];

    for (int r = 0; r < 32; ++r) {
        long row = row0 + r;
        unsigned Wn = 0u;
        if (r < 31) {
            long rown = row + 1;
            int t2n  = (int)(rown >> 16);
            int b2n  = (int)(rown >> 6) & 1023;
            int hw2n = (int)rown & 63;
            int srn  = (b2n * 4 + (nh >> 1)) * 64 + (nh & 1) * 32 + t2n * 8 + (hw2n >> 3);
            Wn = AM[(long)srn * 8 + (hw2n & 7)];
        }
        float4 val = base;
        if (__ballot(W != 0u) != 0ull) {
            #pragma unroll 1
            for (int n2 = 0; n2 < 8; ++n2) {
                unsigned Wx = __shfl(W, n2 * 8);
                while (Wx) {
                    int hd = __ffs(Wx) - 1;
                    Wx &= (Wx - 1);
                    float4 wl = ((const float4*)(WpT + (n2 * 32 + hd) * 256))[lane];
                    val.x += wl.x; val.y += wl.y; val.z += wl.z; val.w += wl.w;
                }
            }
        }
        ((float4*)y)[row * 64 + lane]        = val;
        ((float4*)attn_out)[row * 64 + lane] = z;
        W = Wn;
    }
}

extern "C" void kernel_launch(void* const* d_in, const int* in_sizes, int n_in,
                              void* d_out, int out_size, void* d_ws, size_t ws_size,
                              hipStream_t stream) {
    const float* x   = (const float*)d_in[0];
    const float* Wq  = (const float*)d_in[1];
    const float* Wk  = (const float*)d_in[2];
    const float* Wp  = (const float*)d_in[3];
    const float* bp  = (const float*)d_in[4];
    const float* pos = (const float*)d_in[5];

    float* y        = (float*)d_out;
    float* attn_out = y + 67108864L;

    char* ws = (char*)d_ws;
    unsigned*           AM   = (unsigned*)(ws);
    __hip_bfloat16*     WqT  = (__hip_bfloat16*)(ws + (8L << 20));
    __hip_bfloat16*     WkT  = (__hip_bfloat16*)(ws + (8L << 20) + (128L << 10));
    float*              WpT  = (float*)(ws + (8L << 20) + (256L << 10));
    unsigned*           flag = (unsigned*)(ws + (8L << 20) + (512L << 10));

    prep_kernel<<<256, 256, 0, stream>>>(Wq, Wk, Wp, WqT, WkT, WpT, flag);
    lif_qk_kernel<<<4096, 256, 0, stream>>>(x, AM, WqT, WkT, pos, flag);
    out_kernel<<<2048, 256, 0, stream>>>(AM, WpT, bp, flag, y, attn_out);
}